// Round 10
// baseline (206.496 us; speedup 1.0000x reference)
//
#include <hip/hip_runtime.h>
#include <hip/hip_bf16.h>
#include <stdint.h>

// Problem constants
#define N_NODES 8192
#define N_EDGES 16384
#define N_GRAPHS 512
#define IN_DIM 235
#define H_DIM 64
#define ED_DIM 52
#define HID1 128          // edge-MLP hidden width (W1 rows)
#define KP 256            // K padded 235 -> 256 for MFMA tiling
#define NB 3328           // H_DIM * ED_DIM = P column count

// P column layout: c = (d>>2)*256 + h*4 + (d&3)  [d4-major, h-interleaved]
// -> k_edge lane h reads 13 CONTIGUOUS uint2 blocks (512B/wave-instr).

// k_prep grid partition (940 BT blocks -- R8 showed TLP here is king)
#define BT_BLOCKS 940     // 235 i x 4 h-groups
#define EXT_BLOCKS 128
#define ZERO_BLOCKS 16
#define A_BLOCKS 1024     // A-build vectorized: 8 bf16 per thread
#define PREP_GRID (BT_BLOCKS + EXT_BLOCKS + ZERO_BLOCKS + A_BLOCKS)

#define GEMM_GRID 1728    // 64 m-tiles x 27 n-tiles (pad tile skipped), 8-divisible

typedef __bf16 bf16x8 __attribute__((ext_vector_type(8)));
typedef __bf16 bf16x4_t __attribute__((ext_vector_type(4)));
typedef float f32x4 __attribute__((ext_vector_type(4)));

// Native f32->bf16 cast: RNE; compiler fuses pairs into v_cvt_pk_bf16_f32.
static __device__ inline unsigned short bf16b(float f) {
    __bf16 h = (__bf16)f;
    return __builtin_bit_cast(unsigned short, h);
}

// ---------------------------------------------------------------------------
// K_PREP: fused pre-GEMM work, one dispatch.
// ROUND 10: BT-compose loop INTERCHANGE only (k4 outer, m inner). Old
// m-outer/k4-inner re-read both w1v[k4] and w2v[k4] per m -> 256
// ds_read_b128/thread (986 MB LDS reads chip-wide ~= 12.5us at 128 B/cyc/CU).
// New: w2v[k4] read once, 4 w1 rows per k4 -> 160 reads/thread (1.6x less).
// Same 940-block TLP (R8 lesson), same per-acc FP term order (k4 ascending,
// a.x*b.x+a.y*b.y+... identical) -> bitwise-identical Bt. w1v3 aliases row
// dq for dq>=4; its acc3 is discarded by the existing d<52 store guard.
__global__ __launch_bounds__(256) void k_prep(const float* __restrict__ x,
                                              const float* __restrict__ W1,
                                              const float* __restrict__ W2,
                                              const float* __restrict__ b1,
                                              const float* __restrict__ b2,
                                              const float* __restrict__ root,
                                              unsigned short* __restrict__ A,
                                              unsigned short* __restrict__ Bt) {
    __shared__ float w1s[ED_DIM * 132];       // [d][k] padded
    __shared__ float w2s[16 * 132];           // [hh][k] padded
    const int bx = blockIdx.x;
    const int t = threadIdx.x;

    if (bx < BT_BLOCKS) {
        // C[i][(h,d)] = sum_k W2[(i*64+h)*128+k]*W1[k*52+d], stored at
        // Bt[p][i] with p = (d>>2)*256 + h*4 + (d&3).
        const int i = bx >> 2;                // 0..234
        const int by = bx & 3;                // h base by*16
        for (int j = t; j < ED_DIM * HID1; j += 256) {
            const int k = j / ED_DIM, d = j - k * ED_DIM;
            w1s[d * 132 + k] = W1[j];
        }
        const float* w2src = W2 + ((size_t)i * 64 + by * 16) * HID1;
        for (int j = t; j < 16 * HID1; j += 256) w2s[(j >> 7) * 132 + (j & 127)] = w2src[j];
        __syncthreads();
        const int hh = t & 15, dq = t >> 4;
        const int h = by * 16 + hh;
        const float4* w2v = (const float4*)&w2s[hh * 132];
        const float4* w1v0 = (const float4*)&w1s[(dq +  0) * 132];
        const float4* w1v1 = (const float4*)&w1s[(dq + 16) * 132];
        const float4* w1v2 = (const float4*)&w1s[(dq + 32) * 132];
        const float4* w1v3 = (const float4*)&w1s[((dq < 4) ? (dq + 48) : dq) * 132];
        float ac0 = 0.f, ac1 = 0.f, ac2 = 0.f, ac3 = 0.f;
        #pragma unroll
        for (int k4 = 0; k4 < HID1 / 4; ++k4) {
            const float4 b  = w2v[k4];
            const float4 a0 = w1v0[k4], a1 = w1v1[k4];
            const float4 a2 = w1v2[k4], a3 = w1v3[k4];
            ac0 += a0.x * b.x + a0.y * b.y + a0.z * b.z + a0.w * b.w;
            ac1 += a1.x * b.x + a1.y * b.y + a1.z * b.z + a1.w * b.w;
            ac2 += a2.x * b.x + a2.y * b.y + a2.z * b.z + a2.w * b.w;
            ac3 += a3.x * b.x + a3.y * b.y + a3.z * b.z + a3.w * b.w;
        }
        const float accs[4] = { ac0, ac1, ac2, ac3 };
        #pragma unroll
        for (int m = 0; m < 4; ++m) {
            const int d = dq + m * 16;
            if (d < ED_DIM) {
                const int p = ((d >> 2) << 8) + h * 4 + (d & 3);
                Bt[(size_t)p * KP + i] = bf16b(accs[m]);
            }
        }
    } else if (bx < BT_BLOCKS + EXT_BLOCKS) {
        // ext cols: 3328+j (j<64) = root[:,j]; 3392+j = bc[:,j-64]
        const int j = bx - BT_BLOCKS;         // 0..127
        const int i = t;                      // 0..255
        if (i < IN_DIM) {
            float v;
            if (j < 64) {
                v = root[i * H_DIM + j];
            } else {
                const int jj = i * H_DIM + (j - 64);
                float acc = b2[jj];
                const float4* w = (const float4*)(W2 + (size_t)jj * HID1);
                const float4* bv = (const float4*)b1;
                #pragma unroll
                for (int k4 = 0; k4 < HID1 / 4; ++k4) {
                    const float4 a = w[k4], b = bv[k4];
                    acc += a.x * b.x; acc += a.y * b.y; acc += a.z * b.z; acc += a.w * b.w;
                }
                v = acc;
            }
            Bt[(size_t)(NB + j) * KP + i] = bf16b(v);
        }
    } else if (bx < BT_BLOCKS + EXT_BLOCKS + ZERO_BLOCKS) {
        // Bt pad-col zeroing: rows 0..3455, cols 235..255 (rows 3456+ never read)
        const int z = bx - BT_BLOCKS - EXT_BLOCKS;
        const int TOT = 3456 * 21;
        for (int idx = z * 256 + t; idx < TOT; idx += ZERO_BLOCKS * 256) {
            const int r = idx / 21, c = IN_DIM + idx - r * 21;
            Bt[(size_t)r * KP + c] = 0;
        }
    } else {
        // A build: x (fp32) -> A (bf16 [8192,256], cols >=235 zero), 8/thread
        const int j8 = (bx - BT_BLOCKS - EXT_BLOCKS - ZERO_BLOCKS) * 256 + t;
        const int n = j8 >> 5, i0 = (j8 & 31) * 8;
        const float* xr = x + (size_t)n * IN_DIM;
        union { unsigned short us[8]; uint4 q; } pk;
        #pragma unroll
        for (int k = 0; k < 8; ++k) {
            const int i = i0 + k;
            pk.us[k] = (i < IN_DIM) ? bf16b(xr[i]) : (unsigned short)0;
        }
        *(uint4*)(&A[(size_t)j8 * 8]) = pk.q;
    }
}

// ---------------------------------------------------------------------------
// K2: [8192,256] x [256,3456] GEMM (exact R5 183.6us baseline; R9's
// counted-vmcnt variant reverted -- neutral at this short-K 2-phase shape,
// measured 414 TF vs ~300 TF expectation from the guide's m102 shape curve).
__global__ __launch_bounds__(256) void k_gemm(const unsigned short* __restrict__ A,
                                              const unsigned short* __restrict__ Bt,
                                              unsigned short* __restrict__ P,
                                              float* __restrict__ agg,
                                              float* __restrict__ xb2,
                                              const float* __restrict__ conv_b) {
    __shared__ unsigned short As[2 * 128 * 32];   // 16 KB dbuf
    __shared__ unsigned short Bs[2 * 128 * 32];   // 16 KB dbuf
    const int t = threadIdx.x;
    const int lin = blockIdx.x;                   // 0..1727
    const int xcd = lin & 7, bi = lin >> 3;       // 216 blocks per XCD
    const int mt = (bi / 27) * 8 + xcd;           // 0..63
    const int nt = bi % 27;                       // 0..26
    const int m0 = mt * 128, n0 = nt * 128;
    const int wid = t >> 6, lane = t & 63;
    const int wm = wid & 1;          // 0..1 : 64-row half
    const int wn = wid >> 1;         // 0..1 : 64-col half
    const int q = lane >> 4, r16 = lane & 15;

    f32x4 acc[4][4] = {};

    auto stage = [&](int k0, int buf) {
        #pragma unroll
        for (int s = 0; s < 2; ++s) {
            const int idx = s * 256 + t;          // 0..511, one 16B slot each
            const int row = idx >> 2;             // 0..127
            const int lgrp = ((idx & 3) ^ ((row >> 1) & 3)) * 8;  // logical k-chunk
            const unsigned short* ga = &A[(size_t)(m0 + row) * KP + k0 + lgrp];
            const unsigned short* gb = &Bt[(size_t)(n0 + row) * KP + k0 + lgrp];
            char* la = (char*)As + buf * 8192 + s * 4096 + wid * 1024;
            char* lb = (char*)Bs + buf * 8192 + s * 4096 + wid * 1024;
            __builtin_amdgcn_global_load_lds(
                (const __attribute__((address_space(1))) unsigned int*)ga,
                (__attribute__((address_space(3))) unsigned int*)la, 16, 0, 0);
            __builtin_amdgcn_global_load_lds(
                (const __attribute__((address_space(1))) unsigned int*)gb,
                (__attribute__((address_space(3))) unsigned int*)lb, 16, 0, 0);
        }
    };

    stage(0, 0);
    const int pcq = (q ^ ((r16 >> 1) & 3)) * 8;       // physical chunk for logical q
    #pragma unroll
    for (int it = 0; it < 8; ++it) {
        __syncthreads();                              // drains prefetch for buf[it&1]
        if (it < 7) stage((it + 1) * 32, (it + 1) & 1);
        const int bo = (it & 1) * 4096;               // buffer offset in shorts
        bf16x8 af[4], bfr[4];
        #pragma unroll
        for (int mi = 0; mi < 4; ++mi)
            af[mi] = *(const bf16x8*)(&As[bo + (wm * 64 + mi * 16 + r16) * 32 + pcq]);
        #pragma unroll
        for (int ni = 0; ni < 4; ++ni)
            bfr[ni] = *(const bf16x8*)(&Bs[bo + (wn * 64 + ni * 16 + r16) * 32 + pcq]);
        #pragma unroll
        for (int mi = 0; mi < 4; ++mi)
            #pragma unroll
            for (int ni = 0; ni < 4; ++ni)
                acc[mi][ni] = __builtin_amdgcn_mfma_f32_16x16x32_bf16(
                    bfr[ni], af[mi], acc[mi][ni], 0, 0, 0);   // transposed D
    }

    // Transposed D: lane (q,r16) holds rows m = mi*16+r16, cols n = ni*16+q*4..+3
    if (nt < 26) {
        #pragma unroll
        for (int mi = 0; mi < 4; ++mi)
            #pragma unroll
            for (int ni = 0; ni < 4; ++ni) {
                const int row = m0 + wm * 64 + mi * 16 + r16;
                const int col = n0 + wn * 64 + ni * 16 + q * 4;
                bf16x4_t pk;
                pk[0] = (__bf16)acc[mi][ni][0];
                pk[1] = (__bf16)acc[mi][ni][1];
                pk[2] = (__bf16)acc[mi][ni][2];
                pk[3] = (__bf16)acc[mi][ni][3];
                *(bf16x4_t*)(&P[(size_t)row * NB + col]) = pk;
            }
    } else {
        // ext tile: local col cl = ni*16 + q*4; wn==0 -> agg(+conv_b), else xb2
        #pragma unroll
        for (int mi = 0; mi < 4; ++mi)
            #pragma unroll
            for (int ni = 0; ni < 4; ++ni) {
                const int row = m0 + wm * 64 + mi * 16 + r16;
                const int cl = ni * 16 + q * 4;       // 0..63 within the half
                if (wn == 0) {
                    const float4 cb = *(const float4*)&conv_b[cl];
                    float4 v;
                    v.x = acc[mi][ni][0] + cb.x; v.y = acc[mi][ni][1] + cb.y;
                    v.z = acc[mi][ni][2] + cb.z; v.w = acc[mi][ni][3] + cb.w;
                    *(float4*)(&agg[row * H_DIM + cl]) = v;
                } else {
                    float4 v;
                    v.x = acc[mi][ni][0]; v.y = acc[mi][ni][1];
                    v.z = acc[mi][ni][2]; v.w = acc[mi][ni][3];
                    *(float4*)(&xb2[row * H_DIM + cl]) = v;
                }
            }
    }
}

// ---------------------------------------------------------------------------
// K4: per edge (one wave, lane=h). d4-major P: 13 contiguous uint2 loads.
// (exact R5 baseline)
__global__ __launch_bounds__(256) void k_edge(const int* __restrict__ ei,
                                              const float* __restrict__ ea,
                                              const unsigned short* __restrict__ P,
                                              const float* __restrict__ xb2,
                                              float* __restrict__ agg) {
    const int e = (blockIdx.x * 256 + threadIdx.x) >> 6;
    const int h = threadIdx.x & 63;
    if (e >= N_EDGES) return;
    const int s = ei[e], dst = ei[N_EDGES + e];
    const uint2* Pr = (const uint2*)(P + (size_t)s * NB);
    const float4* ev = (const float4*)(ea + (size_t)e * ED_DIM);

    uint2 pv[13];
    #pragma unroll
    for (int j = 0; j < 13; ++j) pv[j] = Pr[j * 64 + h];
    float4 eav[13];
    #pragma unroll
    for (int j = 0; j < 13; ++j) eav[j] = ev[j];

    float acc = xb2[s * H_DIM + h];
    #pragma unroll
    for (int j = 0; j < 13; ++j) {
        union { unsigned u; float f; } a0, a1, b0, b1;
        a0.u = pv[j].x << 16; a1.u = pv[j].x & 0xffff0000u;
        b0.u = pv[j].y << 16; b1.u = pv[j].y & 0xffff0000u;
        acc += eav[j].x * a0.f + eav[j].y * a1.f
             + eav[j].z * b0.f + eav[j].w * b1.f;
    }
    atomicAdd(&agg[dst * H_DIM + h], acc);
}

// ---------------------------------------------------------------------------
// K_TAIL: fused relu + mean-pool + MLP head, one block per graph.
// (exact R5 baseline)
__global__ __launch_bounds__(256) void k_tail(const float* __restrict__ agg,
                                              const int* __restrict__ batch,
                                              const float* __restrict__ fw1, const float* __restrict__ fb1,
                                              const float* __restrict__ fw2, const float* __restrict__ fb2,
                                              const float* __restrict__ fw3, const float* __restrict__ fb3,
                                              const float* __restrict__ fw4, const float* __restrict__ fb4,
                                              float* __restrict__ out) {
    __shared__ __align__(16) float red[256];
    __shared__ __align__(16) float sp[64];
    __shared__ __align__(16) float s1[128];
    __shared__ __align__(16) float s2[256];
    __shared__ __align__(16) float s3[128];
    const int g = blockIdx.x, t = threadIdx.x;

    int lo = 0, hi = N_NODES;
    while (lo < hi) { const int mid = (lo + hi) >> 1; if (batch[mid] < g) lo = mid + 1; else hi = mid; }
    const int start = lo;
    hi = N_NODES;
    while (lo < hi) { const int mid = (lo + hi) >> 1; if (batch[mid] <= g) lo = mid + 1; else hi = mid; }
    const int end = lo;
    const float inv = 1.0f / fmaxf((float)(end - start), 1.0f);

    float a = 0.f;
    for (int n = start + (t >> 6); n < end; n += 4)
        a += fmaxf(agg[n * H_DIM + (t & 63)], 0.f);
    red[t] = a;
    __syncthreads();
    if (t < 64) sp[t] = (red[t] + red[t + 64] + red[t + 128] + red[t + 192]) * inv;
    __syncthreads();

    if (t < 128) {
        float acc = fb1[t];
        const float4* w = (const float4*)(fw1 + t * 64);
        const float4* sv = (const float4*)sp;
        #pragma unroll
        for (int k = 0; k < 16; ++k) {
            const float4 a4 = w[k], b4 = sv[k];
            acc += a4.x * b4.x; acc += a4.y * b4.y; acc += a4.z * b4.z; acc += a4.w * b4.w;
        }
        s1[t] = fmaxf(acc, 0.f);
    }
    __syncthreads();
    {
        float acc = fb2[t];
        const float4* w = (const float4*)(fw2 + t * 128);
        const float4* sv = (const float4*)s1;
        #pragma unroll
        for (int k = 0; k < 32; ++k) {
            const float4 a4 = w[k], b4 = sv[k];
            acc += a4.x * b4.x; acc += a4.y * b4.y; acc += a4.z * b4.z; acc += a4.w * b4.w;
        }
        s2[t] = fmaxf(acc, 0.f);
    }
    __syncthreads();
    if (t < 128) {
        float acc = fb3[t];
        const float4* w = (const float4*)(fw3 + t * 256);
        const float4* sv = (const float4*)s2;
        #pragma unroll
        for (int k = 0; k < 64; ++k) {
            const float4 a4 = w[k], b4 = sv[k];
            acc += a4.x * b4.x; acc += a4.y * b4.y; acc += a4.z * b4.z; acc += a4.w * b4.w;
        }
        s3[t] = fmaxf(acc, 0.f);
    }
    __syncthreads();
    if (t < 64) {
        float p = s3[t] * fw4[t] + s3[t + 64] * fw4[t + 64];
        #pragma unroll
        for (int off = 32; off > 0; off >>= 1) p += __shfl_down(p, off);
        if (t == 0) out[g] = p + fb4[0];
    }
}

// ---------------------------------------------------------------------------
extern "C" void kernel_launch(void* const* d_in, const int* in_sizes, int n_in,
                              void* d_out, int out_size, void* d_ws, size_t ws_size,
                              hipStream_t stream) {
    const float* x      = (const float*)d_in[0];
    const int*   ei     = (const int*)d_in[1];
    const float* ea     = (const float*)d_in[2];
    const int*   batch  = (const int*)d_in[3];
    const float* W1     = (const float*)d_in[4];
    const float* b1     = (const float*)d_in[5];
    const float* W2     = (const float*)d_in[6];
    const float* b2     = (const float*)d_in[7];
    const float* root   = (const float*)d_in[8];
    const float* conv_b = (const float*)d_in[9];
    const float* fw1 = (const float*)d_in[10]; const float* fb1 = (const float*)d_in[11];
    const float* fw2 = (const float*)d_in[12]; const float* fb2 = (const float*)d_in[13];
    const float* fw3 = (const float*)d_in[14]; const float* fb3 = (const float*)d_in[15];
    const float* fw4 = (const float*)d_in[16]; const float* fb4 = (const float*)d_in[17];
    float* out = (float*)d_out;

    char* ws = (char*)d_ws;
    // workspace layout (16B-aligned), total ~64.8 MB
    unsigned short* A   = (unsigned short*)(ws);             // 8192*256*2   = 4,194,304
    unsigned short* Bt  = (unsigned short*)(ws + 4194304);   // 3584*256*2   = 1,835,008
    unsigned short* P   = (unsigned short*)(ws + 6029312);   // 8192*3328*2  = 54,525,952
    float* agg  = (float*)(ws + 60555264);                   // 8192*64*4    = 2,097,152
    float* xb2  = (float*)(ws + 62652416);                   // 8192*64*4    = 2,097,152

    k_prep<<<dim3(PREP_GRID), dim3(256), 0, stream>>>(x, W1, W2, b1, b2, root, A, Bt);
    k_gemm<<<dim3(GEMM_GRID), dim3(256), 0, stream>>>(A, Bt, P, agg, xb2, conv_b);
    k_edge<<<dim3(N_EDGES / 4), dim3(256), 0, stream>>>(ei, ea, P, xb2, agg);
    k_tail<<<dim3(N_GRAPHS), dim3(256), 0, stream>>>(agg, batch, fw1, fb1, fw2, fb2, fw3, fb3, fw4, fb4, out);
}

// Round 11
// 185.807 us; speedup vs baseline: 1.1113x; 1.1113x over previous
//
#include <hip/hip_runtime.h>
#include <hip/hip_bf16.h>
#include <stdint.h>

// Problem constants
#define N_NODES 8192
#define N_EDGES 16384
#define N_GRAPHS 512
#define IN_DIM 235
#define H_DIM 64
#define ED_DIM 52
#define HID1 128          // edge-MLP hidden width (W1 rows)
#define KP 256            // K padded 235 -> 256 for MFMA tiling
#define NB 3328           // H_DIM * ED_DIM = P column count

// P column layout: c = (d>>2)*256 + h*4 + (d&3)  [d4-major, h-interleaved]
// -> k_edge lane h reads 13 CONTIGUOUS uint2 blocks (512B/wave-instr).

// k_prep grid partition (940 BT blocks -- R8 showed TLP here is king)
#define BT_BLOCKS 940     // 235 i x 4 h-groups
#define EXT_BLOCKS 128
#define ZERO_BLOCKS 16
#define A_BLOCKS 1024     // A-build vectorized: 8 bf16 per thread
#define PREP_GRID (BT_BLOCKS + EXT_BLOCKS + ZERO_BLOCKS + A_BLOCKS)

#define GEMM_GRID 1728    // 64 m-tiles x 27 n-tiles (pad tile skipped), 8-divisible

typedef __bf16 bf16x8 __attribute__((ext_vector_type(8)));
typedef __bf16 bf16x4_t __attribute__((ext_vector_type(4)));
typedef float f32x4 __attribute__((ext_vector_type(4)));

// Native f32->bf16 cast: RNE; compiler fuses pairs into v_cvt_pk_bf16_f32.
static __device__ inline unsigned short bf16b(float f) {
    __bf16 h = (__bf16)f;
    return __builtin_bit_cast(unsigned short, h);
}

// ---------------------------------------------------------------------------
// K_PREP: fused pre-GEMM work, one dispatch.
// ROUND 11: R10's k4-outer interchange (verified bitwise-correct; 160 vs 256
// ds_read_b128/thread) + BOUNDED unroll. R10's full unroll hoisted all loads
// -> VGPR=256, occupancy 2.3%, 42.6us (profile-caught). unroll 2 keeps ~10
// live float4 (~40 VGPR window) -> high occupancy AND the 1.6x LDS-read cut.
__global__ __launch_bounds__(256) void k_prep(const float* __restrict__ x,
                                              const float* __restrict__ W1,
                                              const float* __restrict__ W2,
                                              const float* __restrict__ b1,
                                              const float* __restrict__ b2,
                                              const float* __restrict__ root,
                                              unsigned short* __restrict__ A,
                                              unsigned short* __restrict__ Bt) {
    __shared__ float w1s[ED_DIM * 132];       // [d][k] padded
    __shared__ float w2s[16 * 132];           // [hh][k] padded
    const int bx = blockIdx.x;
    const int t = threadIdx.x;

    if (bx < BT_BLOCKS) {
        // C[i][(h,d)] = sum_k W2[(i*64+h)*128+k]*W1[k*52+d], stored at
        // Bt[p][i] with p = (d>>2)*256 + h*4 + (d&3).
        const int i = bx >> 2;                // 0..234
        const int by = bx & 3;                // h base by*16
        for (int j = t; j < ED_DIM * HID1; j += 256) {
            const int k = j / ED_DIM, d = j - k * ED_DIM;
            w1s[d * 132 + k] = W1[j];
        }
        const float* w2src = W2 + ((size_t)i * 64 + by * 16) * HID1;
        for (int j = t; j < 16 * HID1; j += 256) w2s[(j >> 7) * 132 + (j & 127)] = w2src[j];
        __syncthreads();
        const int hh = t & 15, dq = t >> 4;
        const int h = by * 16 + hh;
        const float4* w2v = (const float4*)&w2s[hh * 132];
        const float4* w1v0 = (const float4*)&w1s[(dq +  0) * 132];
        const float4* w1v1 = (const float4*)&w1s[(dq + 16) * 132];
        const float4* w1v2 = (const float4*)&w1s[(dq + 32) * 132];
        const float4* w1v3 = (const float4*)&w1s[((dq < 4) ? (dq + 48) : dq) * 132];
        float ac0 = 0.f, ac1 = 0.f, ac2 = 0.f, ac3 = 0.f;
        #pragma unroll 2
        for (int k4 = 0; k4 < HID1 / 4; ++k4) {
            const float4 b  = w2v[k4];
            const float4 a0 = w1v0[k4], a1 = w1v1[k4];
            const float4 a2 = w1v2[k4], a3 = w1v3[k4];
            ac0 += a0.x * b.x + a0.y * b.y + a0.z * b.z + a0.w * b.w;
            ac1 += a1.x * b.x + a1.y * b.y + a1.z * b.z + a1.w * b.w;
            ac2 += a2.x * b.x + a2.y * b.y + a2.z * b.z + a2.w * b.w;
            ac3 += a3.x * b.x + a3.y * b.y + a3.z * b.z + a3.w * b.w;
        }
        const float accs[4] = { ac0, ac1, ac2, ac3 };
        #pragma unroll
        for (int m = 0; m < 4; ++m) {
            const int d = dq + m * 16;
            if (d < ED_DIM) {
                const int p = ((d >> 2) << 8) + h * 4 + (d & 3);
                Bt[(size_t)p * KP + i] = bf16b(accs[m]);
            }
        }
    } else if (bx < BT_BLOCKS + EXT_BLOCKS) {
        // ext cols: 3328+j (j<64) = root[:,j]; 3392+j = bc[:,j-64]
        const int j = bx - BT_BLOCKS;         // 0..127
        const int i = t;                      // 0..255
        if (i < IN_DIM) {
            float v;
            if (j < 64) {
                v = root[i * H_DIM + j];
            } else {
                const int jj = i * H_DIM + (j - 64);
                float acc = b2[jj];
                const float4* w = (const float4*)(W2 + (size_t)jj * HID1);
                const float4* bv = (const float4*)b1;
                #pragma unroll
                for (int k4 = 0; k4 < HID1 / 4; ++k4) {
                    const float4 a = w[k4], b = bv[k4];
                    acc += a.x * b.x; acc += a.y * b.y; acc += a.z * b.z; acc += a.w * b.w;
                }
                v = acc;
            }
            Bt[(size_t)(NB + j) * KP + i] = bf16b(v);
        }
    } else if (bx < BT_BLOCKS + EXT_BLOCKS + ZERO_BLOCKS) {
        // Bt pad-col zeroing: rows 0..3455, cols 235..255 (rows 3456+ never read)
        const int z = bx - BT_BLOCKS - EXT_BLOCKS;
        const int TOT = 3456 * 21;
        for (int idx = z * 256 + t; idx < TOT; idx += ZERO_BLOCKS * 256) {
            const int r = idx / 21, c = IN_DIM + idx - r * 21;
            Bt[(size_t)r * KP + c] = 0;
        }
    } else {
        // A build: x (fp32) -> A (bf16 [8192,256], cols >=235 zero), 8/thread
        const int j8 = (bx - BT_BLOCKS - EXT_BLOCKS - ZERO_BLOCKS) * 256 + t;
        const int n = j8 >> 5, i0 = (j8 & 31) * 8;
        const float* xr = x + (size_t)n * IN_DIM;
        union { unsigned short us[8]; uint4 q; } pk;
        #pragma unroll
        for (int k = 0; k < 8; ++k) {
            const int i = i0 + k;
            pk.us[k] = (i < IN_DIM) ? bf16b(xr[i]) : (unsigned short)0;
        }
        *(uint4*)(&A[(size_t)j8 * 8]) = pk.q;
    }
}

// ---------------------------------------------------------------------------
// K2: [8192,256] x [256,3456] GEMM (exact R5 183.6us baseline; measured
// ~35us via R7 decomposition, above the guide's m102 shape-curve expectation
// for this structure -- both restructure attempts were neutral).
__global__ __launch_bounds__(256) void k_gemm(const unsigned short* __restrict__ A,
                                              const unsigned short* __restrict__ Bt,
                                              unsigned short* __restrict__ P,
                                              float* __restrict__ agg,
                                              float* __restrict__ xb2,
                                              const float* __restrict__ conv_b) {
    __shared__ unsigned short As[2 * 128 * 32];   // 16 KB dbuf
    __shared__ unsigned short Bs[2 * 128 * 32];   // 16 KB dbuf
    const int t = threadIdx.x;
    const int lin = blockIdx.x;                   // 0..1727
    const int xcd = lin & 7, bi = lin >> 3;       // 216 blocks per XCD
    const int mt = (bi / 27) * 8 + xcd;           // 0..63
    const int nt = bi % 27;                       // 0..26
    const int m0 = mt * 128, n0 = nt * 128;
    const int wid = t >> 6, lane = t & 63;
    const int wm = wid & 1;          // 0..1 : 64-row half
    const int wn = wid >> 1;         // 0..1 : 64-col half
    const int q = lane >> 4, r16 = lane & 15;

    f32x4 acc[4][4] = {};

    auto stage = [&](int k0, int buf) {
        #pragma unroll
        for (int s = 0; s < 2; ++s) {
            const int idx = s * 256 + t;          // 0..511, one 16B slot each
            const int row = idx >> 2;             // 0..127
            const int lgrp = ((idx & 3) ^ ((row >> 1) & 3)) * 8;  // logical k-chunk
            const unsigned short* ga = &A[(size_t)(m0 + row) * KP + k0 + lgrp];
            const unsigned short* gb = &Bt[(size_t)(n0 + row) * KP + k0 + lgrp];
            char* la = (char*)As + buf * 8192 + s * 4096 + wid * 1024;
            char* lb = (char*)Bs + buf * 8192 + s * 4096 + wid * 1024;
            __builtin_amdgcn_global_load_lds(
                (const __attribute__((address_space(1))) unsigned int*)ga,
                (__attribute__((address_space(3))) unsigned int*)la, 16, 0, 0);
            __builtin_amdgcn_global_load_lds(
                (const __attribute__((address_space(1))) unsigned int*)gb,
                (__attribute__((address_space(3))) unsigned int*)lb, 16, 0, 0);
        }
    };

    stage(0, 0);
    const int pcq = (q ^ ((r16 >> 1) & 3)) * 8;       // physical chunk for logical q
    #pragma unroll
    for (int it = 0; it < 8; ++it) {
        __syncthreads();                              // drains prefetch for buf[it&1]
        if (it < 7) stage((it + 1) * 32, (it + 1) & 1);
        const int bo = (it & 1) * 4096;               // buffer offset in shorts
        bf16x8 af[4], bfr[4];
        #pragma unroll
        for (int mi = 0; mi < 4; ++mi)
            af[mi] = *(const bf16x8*)(&As[bo + (wm * 64 + mi * 16 + r16) * 32 + pcq]);
        #pragma unroll
        for (int ni = 0; ni < 4; ++ni)
            bfr[ni] = *(const bf16x8*)(&Bs[bo + (wn * 64 + ni * 16 + r16) * 32 + pcq]);
        #pragma unroll
        for (int mi = 0; mi < 4; ++mi)
            #pragma unroll
            for (int ni = 0; ni < 4; ++ni)
                acc[mi][ni] = __builtin_amdgcn_mfma_f32_16x16x32_bf16(
                    bfr[ni], af[mi], acc[mi][ni], 0, 0, 0);   // transposed D
    }

    // Transposed D: lane (q,r16) holds rows m = mi*16+r16, cols n = ni*16+q*4..+3
    if (nt < 26) {
        #pragma unroll
        for (int mi = 0; mi < 4; ++mi)
            #pragma unroll
            for (int ni = 0; ni < 4; ++ni) {
                const int row = m0 + wm * 64 + mi * 16 + r16;
                const int col = n0 + wn * 64 + ni * 16 + q * 4;
                bf16x4_t pk;
                pk[0] = (__bf16)acc[mi][ni][0];
                pk[1] = (__bf16)acc[mi][ni][1];
                pk[2] = (__bf16)acc[mi][ni][2];
                pk[3] = (__bf16)acc[mi][ni][3];
                *(bf16x4_t*)(&P[(size_t)row * NB + col]) = pk;
            }
    } else {
        // ext tile: local col cl = ni*16 + q*4; wn==0 -> agg(+conv_b), else xb2
        #pragma unroll
        for (int mi = 0; mi < 4; ++mi)
            #pragma unroll
            for (int ni = 0; ni < 4; ++ni) {
                const int row = m0 + wm * 64 + mi * 16 + r16;
                const int cl = ni * 16 + q * 4;       // 0..63 within the half
                if (wn == 0) {
                    const float4 cb = *(const float4*)&conv_b[cl];
                    float4 v;
                    v.x = acc[mi][ni][0] + cb.x; v.y = acc[mi][ni][1] + cb.y;
                    v.z = acc[mi][ni][2] + cb.z; v.w = acc[mi][ni][3] + cb.w;
                    *(float4*)(&agg[row * H_DIM + cl]) = v;
                } else {
                    float4 v;
                    v.x = acc[mi][ni][0]; v.y = acc[mi][ni][1];
                    v.z = acc[mi][ni][2]; v.w = acc[mi][ni][3];
                    *(float4*)(&xb2[row * H_DIM + cl]) = v;
                }
            }
    }
}

// ---------------------------------------------------------------------------
// K4: per edge (one wave, lane=h). d4-major P: 13 contiguous uint2 loads.
// (exact R5 baseline)
__global__ __launch_bounds__(256) void k_edge(const int* __restrict__ ei,
                                              const float* __restrict__ ea,
                                              const unsigned short* __restrict__ P,
                                              const float* __restrict__ xb2,
                                              float* __restrict__ agg) {
    const int e = (blockIdx.x * 256 + threadIdx.x) >> 6;
    const int h = threadIdx.x & 63;
    if (e >= N_EDGES) return;
    const int s = ei[e], dst = ei[N_EDGES + e];
    const uint2* Pr = (const uint2*)(P + (size_t)s * NB);
    const float4* ev = (const float4*)(ea + (size_t)e * ED_DIM);

    uint2 pv[13];
    #pragma unroll
    for (int j = 0; j < 13; ++j) pv[j] = Pr[j * 64 + h];
    float4 eav[13];
    #pragma unroll
    for (int j = 0; j < 13; ++j) eav[j] = ev[j];

    float acc = xb2[s * H_DIM + h];
    #pragma unroll
    for (int j = 0; j < 13; ++j) {
        union { unsigned u; float f; } a0, a1, b0, b1;
        a0.u = pv[j].x << 16; a1.u = pv[j].x & 0xffff0000u;
        b0.u = pv[j].y << 16; b1.u = pv[j].y & 0xffff0000u;
        acc += eav[j].x * a0.f + eav[j].y * a1.f
             + eav[j].z * b0.f + eav[j].w * b1.f;
    }
    atomicAdd(&agg[dst * H_DIM + h], acc);
}

// ---------------------------------------------------------------------------
// K_TAIL: fused relu + mean-pool + MLP head, one block per graph.
// (exact R5 baseline)
__global__ __launch_bounds__(256) void k_tail(const float* __restrict__ agg,
                                              const int* __restrict__ batch,
                                              const float* __restrict__ fw1, const float* __restrict__ fb1,
                                              const float* __restrict__ fw2, const float* __restrict__ fb2,
                                              const float* __restrict__ fw3, const float* __restrict__ fb3,
                                              const float* __restrict__ fw4, const float* __restrict__ fb4,
                                              float* __restrict__ out) {
    __shared__ __align__(16) float red[256];
    __shared__ __align__(16) float sp[64];
    __shared__ __align__(16) float s1[128];
    __shared__ __align__(16) float s2[256];
    __shared__ __align__(16) float s3[128];
    const int g = blockIdx.x, t = threadIdx.x;

    int lo = 0, hi = N_NODES;
    while (lo < hi) { const int mid = (lo + hi) >> 1; if (batch[mid] < g) lo = mid + 1; else hi = mid; }
    const int start = lo;
    hi = N_NODES;
    while (lo < hi) { const int mid = (lo + hi) >> 1; if (batch[mid] <= g) lo = mid + 1; else hi = mid; }
    const int end = lo;
    const float inv = 1.0f / fmaxf((float)(end - start), 1.0f);

    float a = 0.f;
    for (int n = start + (t >> 6); n < end; n += 4)
        a += fmaxf(agg[n * H_DIM + (t & 63)], 0.f);
    red[t] = a;
    __syncthreads();
    if (t < 64) sp[t] = (red[t] + red[t + 64] + red[t + 128] + red[t + 192]) * inv;
    __syncthreads();

    if (t < 128) {
        float acc = fb1[t];
        const float4* w = (const float4*)(fw1 + t * 64);
        const float4* sv = (const float4*)sp;
        #pragma unroll
        for (int k = 0; k < 16; ++k) {
            const float4 a4 = w[k], b4 = sv[k];
            acc += a4.x * b4.x; acc += a4.y * b4.y; acc += a4.z * b4.z; acc += a4.w * b4.w;
        }
        s1[t] = fmaxf(acc, 0.f);
    }
    __syncthreads();
    {
        float acc = fb2[t];
        const float4* w = (const float4*)(fw2 + t * 128);
        const float4* sv = (const float4*)s1;
        #pragma unroll
        for (int k = 0; k < 32; ++k) {
            const float4 a4 = w[k], b4 = sv[k];
            acc += a4.x * b4.x; acc += a4.y * b4.y; acc += a4.z * b4.z; acc += a4.w * b4.w;
        }
        s2[t] = fmaxf(acc, 0.f);
    }
    __syncthreads();
    if (t < 128) {
        float acc = fb3[t];
        const float4* w = (const float4*)(fw3 + t * 256);
        const float4* sv = (const float4*)s2;
        #pragma unroll
        for (int k = 0; k < 64; ++k) {
            const float4 a4 = w[k], b4 = sv[k];
            acc += a4.x * b4.x; acc += a4.y * b4.y; acc += a4.z * b4.z; acc += a4.w * b4.w;
        }
        s3[t] = fmaxf(acc, 0.f);
    }
    __syncthreads();
    if (t < 64) {
        float p = s3[t] * fw4[t] + s3[t + 64] * fw4[t + 64];
        #pragma unroll
        for (int off = 32; off > 0; off >>= 1) p += __shfl_down(p, off);
        if (t == 0) out[g] = p + fb4[0];
    }
}

// ---------------------------------------------------------------------------
extern "C" void kernel_launch(void* const* d_in, const int* in_sizes, int n_in,
                              void* d_out, int out_size, void* d_ws, size_t ws_size,
                              hipStream_t stream) {
    const float* x      = (const float*)d_in[0];
    const int*   ei     = (const int*)d_in[1];
    const float* ea     = (const float*)d_in[2];
    const int*   batch  = (const int*)d_in[3];
    const float* W1     = (const float*)d_in[4];
    const float* b1     = (const float*)d_in[5];
    const float* W2     = (const float*)d_in[6];
    const float* b2     = (const float*)d_in[7];
    const float* root   = (const float*)d_in[8];
    const float* conv_b = (const float*)d_in[9];
    const float* fw1 = (const float*)d_in[10]; const float* fb1 = (const float*)d_in[11];
    const float* fw2 = (const float*)d_in[12]; const float* fb2 = (const float*)d_in[13];
    const float* fw3 = (const float*)d_in[14]; const float* fb3 = (const float*)d_in[15];
    const float* fw4 = (const float*)d_in[16]; const float* fb4 = (const float*)d_in[17];
    float* out = (float*)d_out;

    char* ws = (char*)d_ws;
    // workspace layout (16B-aligned), total ~64.8 MB
    unsigned short* A   = (unsigned short*)(ws);             // 8192*256*2   = 4,194,304
    unsigned short* Bt  = (unsigned short*)(ws + 4194304);   // 3584*256*2   = 1,835,008
    unsigned short* P   = (unsigned short*)(ws + 6029312);   // 8192*3328*2  = 54,525,952
    float* agg  = (float*)(ws + 60555264);                   // 8192*64*4    = 2,097,152
    float* xb2  = (float*)(ws + 62652416);                   // 8192*64*4    = 2,097,152

    k_prep<<<dim3(PREP_GRID), dim3(256), 0, stream>>>(x, W1, W2, b1, b2, root, A, Bt);
    k_gemm<<<dim3(GEMM_GRID), dim3(256), 0, stream>>>(A, Bt, P, agg, xb2, conv_b);
    k_edge<<<dim3(N_EDGES / 4), dim3(256), 0, stream>>>(ei, ea, P, xb2, agg);
    k_tail<<<dim3(N_GRAPHS), dim3(256), 0, stream>>>(agg, batch, fw1, fb1, fw2, fb2, fw3, fb3, fw4, fb4, out);
}

// Round 12
// 184.620 us; speedup vs baseline: 1.1185x; 1.0064x over previous
//
#include <hip/hip_runtime.h>
#include <hip/hip_bf16.h>
#include <stdint.h>

// Problem constants
#define N_NODES 8192
#define N_EDGES 16384
#define N_GRAPHS 512
#define IN_DIM 235
#define H_DIM 64
#define ED_DIM 52
#define HID1 128          // edge-MLP hidden width (W1 rows)
#define KP 256            // K padded 235 -> 256 for MFMA tiling
#define NB 3328           // H_DIM * ED_DIM = P column count

// P column layout: c = (d>>2)*256 + h*4 + (d&3)  [d4-major, h-interleaved]
// -> k_edge lane h reads 13 CONTIGUOUS uint2 blocks (512B/wave-instr).

// k_prep grid partition
#define BT_BLOCKS 940     // 235 i x 4 h-groups
#define EXT_BLOCKS 128
#define ZERO_BLOCKS 16
#define A_BLOCKS 1024     // A-build vectorized: 8 bf16 per thread
#define PREP_GRID (BT_BLOCKS + EXT_BLOCKS + ZERO_BLOCKS + A_BLOCKS)

#define GEMM_GRID 1728    // 64 m-tiles x 27 n-tiles (pad tile skipped), 8-divisible

typedef __bf16 bf16x8 __attribute__((ext_vector_type(8)));
typedef __bf16 bf16x4_t __attribute__((ext_vector_type(4)));
typedef float f32x4 __attribute__((ext_vector_type(4)));

// Native f32->bf16 cast: RNE; compiler fuses pairs into v_cvt_pk_bf16_f32.
static __device__ inline unsigned short bf16b(float f) {
    __bf16 h = (__bf16)f;
    return __builtin_bit_cast(unsigned short, h);
}

// ---------------------------------------------------------------------------
// K_PREP: fused pre-GEMM work, one dispatch (exact R5 183.6us configuration):
//  blocks [0,940):      Bt live cols (edge-MLP compose, d4-major col order)
//  blocks [940,1068):   ext cols (root / composed bias bc)
//  blocks [1068,1084):  Bt pad-col zeroing (rows 0..3455, cols 235..255)
//  blocks [1084,2108):  A = bf16(x) zero-padded, 8 elts/thread, 16B stores
// Session evidence: latency-bound at high TLP. R8 (1-block-per-i tiling,
// occupancy collapse) -8us; R10 (interchange, full unroll -> VGPR=256) -23us;
// R11 (interchange, unroll 2, healthy VGPR) neutral -> this 940-block
// m-outer form IS the floor for this structure.
__global__ __launch_bounds__(256) void k_prep(const float* __restrict__ x,
                                              const float* __restrict__ W1,
                                              const float* __restrict__ W2,
                                              const float* __restrict__ b1,
                                              const float* __restrict__ b2,
                                              const float* __restrict__ root,
                                              unsigned short* __restrict__ A,
                                              unsigned short* __restrict__ Bt) {
    __shared__ float w1s[ED_DIM * 132];       // [d][k] padded
    __shared__ float w2s[16 * 132];           // [hh][k] padded
    const int bx = blockIdx.x;
    const int t = threadIdx.x;

    if (bx < BT_BLOCKS) {
        // C[i][(h,d)] = sum_k W2[(i*64+h)*128+k]*W1[k*52+d], stored at
        // Bt[p][i] with p = (d>>2)*256 + h*4 + (d&3).
        const int i = bx >> 2;                // 0..234
        const int by = bx & 3;                // h base by*16
        for (int j = t; j < ED_DIM * HID1; j += 256) {
            const int k = j / ED_DIM, d = j - k * ED_DIM;
            w1s[d * 132 + k] = W1[j];
        }
        const float* w2src = W2 + ((size_t)i * 64 + by * 16) * HID1;
        for (int j = t; j < 16 * HID1; j += 256) w2s[(j >> 7) * 132 + (j & 127)] = w2src[j];
        __syncthreads();
        const int hh = t & 15, dq = t >> 4;
        const int h = by * 16 + hh;
        const float4* w2v = (const float4*)&w2s[hh * 132];
        #pragma unroll
        for (int m = 0; m < 4; ++m) {
            const int d = dq + m * 16;
            if (d >= ED_DIM) break;
            const float4* w1v = (const float4*)&w1s[d * 132];
            float acc = 0.f;
            #pragma unroll
            for (int k4 = 0; k4 < HID1 / 4; ++k4) {
                const float4 a = w1v[k4], b = w2v[k4];
                acc += a.x * b.x + a.y * b.y + a.z * b.z + a.w * b.w;
            }
            const int p = ((d >> 2) << 8) + h * 4 + (d & 3);
            Bt[(size_t)p * KP + i] = bf16b(acc);
        }
    } else if (bx < BT_BLOCKS + EXT_BLOCKS) {
        // ext cols: 3328+j (j<64) = root[:,j]; 3392+j = bc[:,j-64]
        const int j = bx - BT_BLOCKS;         // 0..127
        const int i = t;                      // 0..255
        if (i < IN_DIM) {
            float v;
            if (j < 64) {
                v = root[i * H_DIM + j];
            } else {
                const int jj = i * H_DIM + (j - 64);
                float acc = b2[jj];
                const float4* w = (const float4*)(W2 + (size_t)jj * HID1);
                const float4* bv = (const float4*)b1;
                #pragma unroll
                for (int k4 = 0; k4 < HID1 / 4; ++k4) {
                    const float4 a = w[k4], b = bv[k4];
                    acc += a.x * b.x; acc += a.y * b.y; acc += a.z * b.z; acc += a.w * b.w;
                }
                v = acc;
            }
            Bt[(size_t)(NB + j) * KP + i] = bf16b(v);
        }
    } else if (bx < BT_BLOCKS + EXT_BLOCKS + ZERO_BLOCKS) {
        // Bt pad-col zeroing: rows 0..3455, cols 235..255 (rows 3456+ never read)
        const int z = bx - BT_BLOCKS - EXT_BLOCKS;
        const int TOT = 3456 * 21;
        for (int idx = z * 256 + t; idx < TOT; idx += ZERO_BLOCKS * 256) {
            const int r = idx / 21, c = IN_DIM + idx - r * 21;
            Bt[(size_t)r * KP + c] = 0;
        }
    } else {
        // A build: x (fp32) -> A (bf16 [8192,256], cols >=235 zero), 8/thread
        const int j8 = (bx - BT_BLOCKS - EXT_BLOCKS - ZERO_BLOCKS) * 256 + t;
        const int n = j8 >> 5, i0 = (j8 & 31) * 8;
        const float* xr = x + (size_t)n * IN_DIM;
        union { unsigned short us[8]; uint4 q; } pk;
        #pragma unroll
        for (int k = 0; k < 8; ++k) {
            const int i = i0 + k;
            pk.us[k] = (i < IN_DIM) ? bf16b(xr[i]) : (unsigned short)0;
        }
        *(uint4*)(&A[(size_t)j8 * 8]) = pk.q;
    }
}

// ---------------------------------------------------------------------------
// K2: [8192,256] x [256,3456] GEMM (exact R5 183.6us configuration).
// 128x128 tile / BK=32 / 256 thr, XCD remap (1728 % 8 == 0), prefetch-after-
// barrier dbuf, XOR source swizzle (linear LDS dest for global_load_lds),
// swapped MFMA operands; n-tile 26 = ext tile (agg+conv_b / xb2).
// Session evidence: ~35us measured (R7 x3-repeat); 414 TF effective, above
// the guide's m102 shape-curve for this structure at this shape. Serialized
// counters (R11): MfmaUtil 11.6 / VALU 7.5 / HBM 20.7 / conflicts 0 -- no
// saturated pipe; stalls TLP-hidden (m114). Both restructures (256^2 R0,
// counted-vmcnt R9) measured neutral -> structural floor at 4 K-steps.
__global__ __launch_bounds__(256) void k_gemm(const unsigned short* __restrict__ A,
                                              const unsigned short* __restrict__ Bt,
                                              unsigned short* __restrict__ P,
                                              float* __restrict__ agg,
                                              float* __restrict__ xb2,
                                              const float* __restrict__ conv_b) {
    __shared__ unsigned short As[2 * 128 * 32];   // 16 KB dbuf
    __shared__ unsigned short Bs[2 * 128 * 32];   // 16 KB dbuf
    const int t = threadIdx.x;
    const int lin = blockIdx.x;                   // 0..1727
    const int xcd = lin & 7, bi = lin >> 3;       // 216 blocks per XCD
    const int mt = (bi / 27) * 8 + xcd;           // 0..63
    const int nt = bi % 27;                       // 0..26
    const int m0 = mt * 128, n0 = nt * 128;
    const int wid = t >> 6, lane = t & 63;
    const int wm = wid & 1;          // 0..1 : 64-row half
    const int wn = wid >> 1;         // 0..1 : 64-col half
    const int q = lane >> 4, r16 = lane & 15;

    f32x4 acc[4][4] = {};

    auto stage = [&](int k0, int buf) {
        #pragma unroll
        for (int s = 0; s < 2; ++s) {
            const int idx = s * 256 + t;          // 0..511, one 16B slot each
            const int row = idx >> 2;             // 0..127
            const int lgrp = ((idx & 3) ^ ((row >> 1) & 3)) * 8;  // logical k-chunk
            const unsigned short* ga = &A[(size_t)(m0 + row) * KP + k0 + lgrp];
            const unsigned short* gb = &Bt[(size_t)(n0 + row) * KP + k0 + lgrp];
            char* la = (char*)As + buf * 8192 + s * 4096 + wid * 1024;
            char* lb = (char*)Bs + buf * 8192 + s * 4096 + wid * 1024;
            __builtin_amdgcn_global_load_lds(
                (const __attribute__((address_space(1))) unsigned int*)ga,
                (__attribute__((address_space(3))) unsigned int*)la, 16, 0, 0);
            __builtin_amdgcn_global_load_lds(
                (const __attribute__((address_space(1))) unsigned int*)gb,
                (__attribute__((address_space(3))) unsigned int*)lb, 16, 0, 0);
        }
    };

    stage(0, 0);
    const int pcq = (q ^ ((r16 >> 1) & 3)) * 8;       // physical chunk for logical q
    #pragma unroll
    for (int it = 0; it < 8; ++it) {
        __syncthreads();                              // drains prefetch for buf[it&1]
        if (it < 7) stage((it + 1) * 32, (it + 1) & 1);
        const int bo = (it & 1) * 4096;               // buffer offset in shorts
        bf16x8 af[4], bfr[4];
        #pragma unroll
        for (int mi = 0; mi < 4; ++mi)
            af[mi] = *(const bf16x8*)(&As[bo + (wm * 64 + mi * 16 + r16) * 32 + pcq]);
        #pragma unroll
        for (int ni = 0; ni < 4; ++ni)
            bfr[ni] = *(const bf16x8*)(&Bs[bo + (wn * 64 + ni * 16 + r16) * 32 + pcq]);
        #pragma unroll
        for (int mi = 0; mi < 4; ++mi)
            #pragma unroll
            for (int ni = 0; ni < 4; ++ni)
                acc[mi][ni] = __builtin_amdgcn_mfma_f32_16x16x32_bf16(
                    bfr[ni], af[mi], acc[mi][ni], 0, 0, 0);   // transposed D
    }

    // Transposed D: lane (q,r16) holds rows m = mi*16+r16, cols n = ni*16+q*4..+3
    if (nt < 26) {
        #pragma unroll
        for (int mi = 0; mi < 4; ++mi)
            #pragma unroll
            for (int ni = 0; ni < 4; ++ni) {
                const int row = m0 + wm * 64 + mi * 16 + r16;
                const int col = n0 + wn * 64 + ni * 16 + q * 4;
                bf16x4_t pk;
                pk[0] = (__bf16)acc[mi][ni][0];
                pk[1] = (__bf16)acc[mi][ni][1];
                pk[2] = (__bf16)acc[mi][ni][2];
                pk[3] = (__bf16)acc[mi][ni][3];
                *(bf16x4_t*)(&P[(size_t)row * NB + col]) = pk;
            }
    } else {
        // ext tile: local col cl = ni*16 + q*4; wn==0 -> agg(+conv_b), else xb2
        #pragma unroll
        for (int mi = 0; mi < 4; ++mi)
            #pragma unroll
            for (int ni = 0; ni < 4; ++ni) {
                const int row = m0 + wm * 64 + mi * 16 + r16;
                const int cl = ni * 16 + q * 4;       // 0..63 within the half
                if (wn == 0) {
                    const float4 cb = *(const float4*)&conv_b[cl];
                    float4 v;
                    v.x = acc[mi][ni][0] + cb.x; v.y = acc[mi][ni][1] + cb.y;
                    v.z = acc[mi][ni][2] + cb.z; v.w = acc[mi][ni][3] + cb.w;
                    *(float4*)(&agg[row * H_DIM + cl]) = v;
                } else {
                    float4 v;
                    v.x = acc[mi][ni][0]; v.y = acc[mi][ni][1];
                    v.z = acc[mi][ni][2]; v.w = acc[mi][ni][3];
                    *(float4*)(&xb2[row * H_DIM + cl]) = v;
                }
            }
    }
}

// ---------------------------------------------------------------------------
// K4: per edge (one wave, lane=h). d4-major P: lane h's j-th uint2 sits at
// uint2 index j*64+h -> each of the 13 loads is 512B contiguous across the
// wave. ~109 MB of L3-resident P-row reads -> BW floor ~10-15us.
__global__ __launch_bounds__(256) void k_edge(const int* __restrict__ ei,
                                              const float* __restrict__ ea,
                                              const unsigned short* __restrict__ P,
                                              const float* __restrict__ xb2,
                                              float* __restrict__ agg) {
    const int e = (blockIdx.x * 256 + threadIdx.x) >> 6;
    const int h = threadIdx.x & 63;
    if (e >= N_EDGES) return;
    const int s = ei[e], dst = ei[N_EDGES + e];
    const uint2* Pr = (const uint2*)(P + (size_t)s * NB);
    const float4* ev = (const float4*)(ea + (size_t)e * ED_DIM);

    uint2 pv[13];
    #pragma unroll
    for (int j = 0; j < 13; ++j) pv[j] = Pr[j * 64 + h];
    float4 eav[13];
    #pragma unroll
    for (int j = 0; j < 13; ++j) eav[j] = ev[j];

    float acc = xb2[s * H_DIM + h];
    #pragma unroll
    for (int j = 0; j < 13; ++j) {
        union { unsigned u; float f; } a0, a1, b0, b1;
        a0.u = pv[j].x << 16; a1.u = pv[j].x & 0xffff0000u;
        b0.u = pv[j].y << 16; b1.u = pv[j].y & 0xffff0000u;
        acc += eav[j].x * a0.f + eav[j].y * a1.f
             + eav[j].z * b0.f + eav[j].w * b1.f;
    }
    atomicAdd(&agg[dst * H_DIM + h], acc);
}

// ---------------------------------------------------------------------------
// K_TAIL: fused relu + mean-pool + MLP head, one block per graph.
// batch is SORTED -> per-graph node range via binary search; no atomics.
// 512 blocks (R6's 4-graph batching cost +7us by serializing pooling).
__global__ __launch_bounds__(256) void k_tail(const float* __restrict__ agg,
                                              const int* __restrict__ batch,
                                              const float* __restrict__ fw1, const float* __restrict__ fb1,
                                              const float* __restrict__ fw2, const float* __restrict__ fb2,
                                              const float* __restrict__ fw3, const float* __restrict__ fb3,
                                              const float* __restrict__ fw4, const float* __restrict__ fb4,
                                              float* __restrict__ out) {
    __shared__ __align__(16) float red[256];
    __shared__ __align__(16) float sp[64];
    __shared__ __align__(16) float s1[128];
    __shared__ __align__(16) float s2[256];
    __shared__ __align__(16) float s3[128];
    const int g = blockIdx.x, t = threadIdx.x;

    int lo = 0, hi = N_NODES;
    while (lo < hi) { const int mid = (lo + hi) >> 1; if (batch[mid] < g) lo = mid + 1; else hi = mid; }
    const int start = lo;
    hi = N_NODES;
    while (lo < hi) { const int mid = (lo + hi) >> 1; if (batch[mid] <= g) lo = mid + 1; else hi = mid; }
    const int end = lo;
    const float inv = 1.0f / fmaxf((float)(end - start), 1.0f);

    float a = 0.f;
    for (int n = start + (t >> 6); n < end; n += 4)
        a += fmaxf(agg[n * H_DIM + (t & 63)], 0.f);
    red[t] = a;
    __syncthreads();
    if (t < 64) sp[t] = (red[t] + red[t + 64] + red[t + 128] + red[t + 192]) * inv;
    __syncthreads();

    if (t < 128) {
        float acc = fb1[t];
        const float4* w = (const float4*)(fw1 + t * 64);
        const float4* sv = (const float4*)sp;
        #pragma unroll
        for (int k = 0; k < 16; ++k) {
            const float4 a4 = w[k], b4 = sv[k];
            acc += a4.x * b4.x; acc += a4.y * b4.y; acc += a4.z * b4.z; acc += a4.w * b4.w;
        }
        s1[t] = fmaxf(acc, 0.f);
    }
    __syncthreads();
    {
        float acc = fb2[t];
        const float4* w = (const float4*)(fw2 + t * 128);
        const float4* sv = (const float4*)s1;
        #pragma unroll
        for (int k = 0; k < 32; ++k) {
            const float4 a4 = w[k], b4 = sv[k];
            acc += a4.x * b4.x; acc += a4.y * b4.y; acc += a4.z * b4.z; acc += a4.w * b4.w;
        }
        s2[t] = fmaxf(acc, 0.f);
    }
    __syncthreads();
    if (t < 128) {
        float acc = fb3[t];
        const float4* w = (const float4*)(fw3 + t * 256);
        const float4* sv = (const float4*)s2;
        #pragma unroll
        for (int k = 0; k < 64; ++k) {
            const float4 a4 = w[k], b4 = sv[k];
            acc += a4.x * b4.x; acc += a4.y * b4.y; acc += a4.z * b4.z; acc += a4.w * b4.w;
        }
        s3[t] = fmaxf(acc, 0.f);
    }
    __syncthreads();
    if (t < 64) {
        float p = s3[t] * fw4[t] + s3[t + 64] * fw4[t + 64];
        #pragma unroll
        for (int off = 32; off > 0; off >>= 1) p += __shfl_down(p, off);
        if (t == 0) out[g] = p + fb4[0];
    }
}

// ---------------------------------------------------------------------------
extern "C" void kernel_launch(void* const* d_in, const int* in_sizes, int n_in,
                              void* d_out, int out_size, void* d_ws, size_t ws_size,
                              hipStream_t stream) {
    const float* x      = (const float*)d_in[0];
    const int*   ei     = (const int*)d_in[1];
    const float* ea     = (const float*)d_in[2];
    const int*   batch  = (const int*)d_in[3];
    const float* W1     = (const float*)d_in[4];
    const float* b1     = (const float*)d_in[5];
    const float* W2     = (const float*)d_in[6];
    const float* b2     = (const float*)d_in[7];
    const float* root   = (const float*)d_in[8];
    const float* conv_b = (const float*)d_in[9];
    const float* fw1 = (const float*)d_in[10]; const float* fb1 = (const float*)d_in[11];
    const float* fw2 = (const float*)d_in[12]; const float* fb2 = (const float*)d_in[13];
    const float* fw3 = (const float*)d_in[14]; const float* fb3 = (const float*)d_in[15];
    const float* fw4 = (const float*)d_in[16]; const float* fb4 = (const float*)d_in[17];
    float* out = (float*)d_out;

    char* ws = (char*)d_ws;
    // workspace layout (16B-aligned), total ~64.8 MB
    unsigned short* A   = (unsigned short*)(ws);             // 8192*256*2   = 4,194,304
    unsigned short* Bt  = (unsigned short*)(ws + 4194304);   // 3584*256*2   = 1,835,008
    unsigned short* P   = (unsigned short*)(ws + 6029312);   // 8192*3328*2  = 54,525,952
    float* agg  = (float*)(ws + 60555264);                   // 8192*64*4    = 2,097,152
    float* xb2  = (float*)(ws + 62652416);                   // 8192*64*4    = 2,097,152

    k_prep<<<dim3(PREP_GRID), dim3(256), 0, stream>>>(x, W1, W2, b1, b2, root, A, Bt);
    k_gemm<<<dim3(GEMM_GRID), dim3(256), 0, stream>>>(A, Bt, P, agg, xb2, conv_b);
    k_edge<<<dim3(N_EDGES / 4), dim3(256), 0, stream>>>(ei, ea, P, xb2, agg);
    k_tail<<<dim3(N_GRAPHS), dim3(256), 0, stream>>>(agg, batch, fw1, fb1, fw2, fb2, fw3, fb3, fw4, fb4, out);
}